// Round 2
// baseline (1806.911 us; speedup 1.0000x reference)
//
#include <hip/hip_runtime.h>
#include <math.h>

constexpr int D = 64;      // input / output feature dim
constexpr int H = 128;     // GRU hidden dim
constexpr int MAXLEN = 512;

__device__ __forceinline__ float sigmoid_(float v) {
    return 1.0f / (1.0f + __expf(-v));
}
__device__ __forceinline__ float tanh_(float v) {
    // tanh(x) = sign(x) * (1 - 2/(exp(2|x|)+1)); robust for large |x|
    float a = fabsf(v);
    float e = __expf(2.0f * a);
    float t = 1.0f - 2.0f / (e + 1.0f);
    return copysignf(t, v);
}

// One block per sequence. 384 threads: thread tid owns gate row tid of the
// stacked [3H, *] weight matrices (g = tid>>7 in {r,z,n}, k = tid&127).
// W rows live in registers; h lives in LDS (uniform broadcast reads).
__global__ __launch_bounds__(384, 1)
void gru_seq_kernel(const float* __restrict__ x,
                    const int* __restrict__ offsets,   // int32! (JAX x64 disabled)
                    const float* __restrict__ W_ih,
                    const float* __restrict__ W_hh,
                    const float* __restrict__ W_dense,
                    const float* __restrict__ b_dense,
                    float* __restrict__ out,
                    int B, int T)
{
    const int b   = blockIdx.x;
    const int tid = threadIdx.x;          // 0..383
    const int g   = tid >> 7;             // 0=r, 1=z, 2=n  (wave-uniform)
    const int k   = tid & 127;

    __shared__ float h_s[H];
    __shared__ float x_s[D];
    __shared__ float r_s[H];
    __shared__ float z_s[H];

    // ---- sequence bounds (lengths = clip(diff, 1, MAXLEN)) ----
    int start = offsets[b];
    int end   = (b == B - 1) ? T : offsets[b + 1];
    int len = end - start;
    if (len < 1) len = 1;
    if (len > MAXLEN) len = MAXLEN;

    // ---- stage this thread's weight rows into registers ----
    float wih[D];
    float whh[H];
    {
        const float* wi = W_ih + (size_t)tid * D;
        const float* wh = W_hh + (size_t)tid * H;
#pragma unroll
        for (int j = 0; j < D; j += 4) {
            float4 v = *(const float4*)(wi + j);
            wih[j] = v.x; wih[j+1] = v.y; wih[j+2] = v.z; wih[j+3] = v.w;
        }
#pragma unroll
        for (int j = 0; j < H; j += 4) {
            float4 v = *(const float4*)(wh + j);
            whh[j] = v.x; whh[j+1] = v.y; whh[j+2] = v.z; whh[j+3] = v.w;
        }
    }

    if (tid < H) h_s[tid] = 0.0f;

    const float* xrow = x + (size_t)start * D;

    // prefetch x_0
    float xv = 0.0f;
    if (tid < D) xv = xrow[tid];

    for (int t = 0; t < len; ++t) {
        if (tid < D) x_s[tid] = xv;
        __syncthreads();                              // x_s, h_s ready

        // prefetch next x row; latency hides under the dot products
        if (tid < D && (t + 1) < len) xv = xrow[(size_t)(t + 1) * D + tid];

        // gi[tid] = x_t . W_ih[tid,:]   (4-way ILP)
        float a0 = 0.f, a1 = 0.f, a2 = 0.f, a3 = 0.f;
#pragma unroll
        for (int j = 0; j < D; j += 4) {
            a0 += x_s[j]     * wih[j];
            a1 += x_s[j + 1] * wih[j + 1];
            a2 += x_s[j + 2] * wih[j + 2];
            a3 += x_s[j + 3] * wih[j + 3];
        }
        float ai = (a0 + a1) + (a2 + a3);

        // gh[tid] = h . W_hh[tid,:]     (8-way ILP)
        float c0=0.f,c1=0.f,c2=0.f,c3=0.f,c4=0.f,c5=0.f,c6=0.f,c7=0.f;
#pragma unroll
        for (int j = 0; j < H; j += 8) {
            c0 += h_s[j]     * whh[j];
            c1 += h_s[j + 1] * whh[j + 1];
            c2 += h_s[j + 2] * whh[j + 2];
            c3 += h_s[j + 3] * whh[j + 3];
            c4 += h_s[j + 4] * whh[j + 4];
            c5 += h_s[j + 5] * whh[j + 5];
            c6 += h_s[j + 6] * whh[j + 6];
            c7 += h_s[j + 7] * whh[j + 7];
        }
        float ah = ((c0 + c1) + (c2 + c3)) + ((c4 + c5) + (c6 + c7));

        if (g == 0) {
            r_s[k] = sigmoid_(ai + ah);               // waves 0-1
        } else if (g == 1) {
            z_s[k] = sigmoid_(ai + ah);               // waves 2-3
        }
        __syncthreads();                              // r_s, z_s ready; dot reads done

        if (g == 2) {                                 // waves 4-5
            float n  = tanh_(ai + r_s[k] * ah);       // n = tanh(inn + r * hn)
            float z  = z_s[k];
            h_s[k]   = (1.0f - z) * n + z * h_s[k];
        }
        // next iteration's first barrier orders h_s write vs. reads
    }
    __syncthreads();                                  // final h ready

    // ---- dense(128 -> 64) + L2 normalize; lanes 0..63 of wave 0 ----
    if (tid < D) {
        const float* wd = W_dense + (size_t)tid * H;
        float d0=0.f,d1=0.f,d2=0.f,d3=0.f;
#pragma unroll
        for (int j = 0; j < H; j += 4) {
            d0 += h_s[j]     * wd[j];
            d1 += h_s[j + 1] * wd[j + 1];
            d2 += h_s[j + 2] * wd[j + 2];
            d3 += h_s[j + 3] * wd[j + 3];
        }
        float v = (d0 + d1) + (d2 + d3) + b_dense[tid];

        float s = v * v;
#pragma unroll
        for (int off = 32; off >= 1; off >>= 1)
            s += __shfl_xor(s, off);                  // 64-lane reduce
        float norm = sqrtf(s);
        out[(size_t)b * D + tid] = v / fmaxf(norm, 1e-12f);
    }
}

extern "C" void kernel_launch(void* const* d_in, const int* in_sizes, int n_in,
                              void* d_out, int out_size, void* d_ws, size_t ws_size,
                              hipStream_t stream) {
    const float* x       = (const float*)d_in[0];
    const int*   offsets = (const int*)d_in[1];      // int32 on device
    const float* W_ih    = (const float*)d_in[2];
    const float* W_hh    = (const float*)d_in[3];
    const float* W_dense = (const float*)d_in[4];
    const float* b_dense = (const float*)d_in[5];
    float*       out     = (float*)d_out;

    const int B = in_sizes[1];            // 2048 sequences
    const int T = in_sizes[0] / D;        // 262144 rows of x

    gru_seq_kernel<<<B, 384, 0, stream>>>(x, offsets, W_ih, W_hh, W_dense, b_dense, out, B, T);
}

// Round 3
// 672.656 us; speedup vs baseline: 2.6862x; 2.6862x over previous
//
#include <hip/hip_runtime.h>
#include <math.h>

constexpr int D = 64;      // input / output feature dim
constexpr int H = 128;     // GRU hidden dim
constexpr int MAXLEN = 512;
constexpr int MSEQ = 16;   // sequences per block (MFMA M dim)

typedef __attribute__((ext_vector_type(8))) short short8;  // 8 bf16 = 4 VGPRs
typedef __attribute__((ext_vector_type(4))) float f32x4;   // MFMA accumulator

__device__ __forceinline__ short f2bf(float f) {           // f32 -> bf16 RNE
    unsigned u = __float_as_uint(f);
    u += 0x7fffu + ((u >> 16) & 1u);
    return (short)(u >> 16);
}
__device__ __forceinline__ short8 pack8(float4 a, float4 b) {
    short8 r;
    r[0]=f2bf(a.x); r[1]=f2bf(a.y); r[2]=f2bf(a.z); r[3]=f2bf(a.w);
    r[4]=f2bf(b.x); r[5]=f2bf(b.y); r[6]=f2bf(b.z); r[7]=f2bf(b.w);
    return r;
}
__device__ __forceinline__ float sigmoid_(float v) { return 1.0f / (1.0f + __expf(-v)); }
__device__ __forceinline__ float tanh_(float v) {
    float a = fabsf(v);
    float e = __expf(2.0f * a);
    float t = 1.0f - 2.0f / (e + 1.0f);
    return copysignf(t, v);
}

#define MFMA(a, b, c) __builtin_amdgcn_mfma_f32_16x16x32_bf16((a), (b), (c), 0, 0, 0)

// 512 threads = 8 waves. Wave w owns gate-column slice [16w, 16w+16) of r,z,n.
// A-frag (lane): m = lane&15, k = (lane>>4)*8 + j (8 consecutive k -> b128 LDS read)
// B-frag (lane): n = lane&15, k = (lane>>4)*8 + j (8 consecutive floats of W row n)
// C/D   (lane): n = lane&15, m = (lane>>4)*4 + reg   [m89 verified]
__global__ __launch_bounds__(512, 2)
void gru_mfma_kernel(const float* __restrict__ x,
                     const int* __restrict__ offsets,
                     const float* __restrict__ W_ih,
                     const float* __restrict__ W_hh,
                     const float* __restrict__ W_dense,
                     const float* __restrict__ b_dense,
                     float* __restrict__ out,
                     int B, int T)
{
    const int bb  = blockIdx.x;
    const int tid = threadIdx.x;
    const int w   = tid >> 6;       // wave 0..7
    const int l   = tid & 63;       // lane
    const int row = l & 15;         // M-row (A) / N-col (B,D) index
    const int q   = l >> 4;         // k-group 0..3
    const int rsw = row & 7;        // XOR swizzle key for A-frag reads

    __shared__ __align__(16) short h_bf[MSEQ * H];        // bf16 h, XOR-swizzled, 4KB
    __shared__ __align__(16) short x_bf[2][MSEQ * D];     // bf16 x, XOR-swizzled, 2x2KB
    __shared__ int slen[MSEQ], sstart[MSEQ];
    __shared__ float h_f32[MSEQ][H];                      // epilogue
    __shared__ float red[512];
    __shared__ float nrm2[MSEQ];

    // ---- per-group sequence bounds ----
    if (tid < MSEQ) {
        int sg = bb * MSEQ + tid;
        int st = 0, en = 1;
        if (sg < B) {
            st = offsets[sg];
            en = (sg + 1 < B) ? offsets[sg + 1] : T;
        }
        int ln = en - st;
        if (ln < 1) ln = 1;
        if (ln > MAXLEN) ln = MAXLEN;
        sstart[tid] = st;
        slen[tid]   = ln;
    }
    // zero h_bf (1024 ints)
    ((int*)h_bf)[tid] = 0;
    ((int*)h_bf)[tid + 512] = 0;
    __syncthreads();

    int nt = 1;
#pragma unroll
    for (int i = 0; i < MSEQ; ++i) nt = max(nt, slen[i]);

    // ---- B-fragments (weights) in registers, loaded once ----
    short8 Bhr[4], Bhz[4], Bhn[4];    // gh: gate x 4 k-tiles (K=128)
    short8 Bir[2], Biz[2], Bin[2];    // gi: gate x 2 k-tiles (K=64)
    {
        const int nr = 0 * H + w * 16 + row;   // W row index per gate (3H rows)
        const int nz = 1 * H + w * 16 + row;
        const int nn = 2 * H + w * 16 + row;
#pragma unroll
        for (int kt = 0; kt < 4; ++kt) {
            const float* pr = W_hh + (size_t)nr * H + kt * 32 + q * 8;
            const float* pz = W_hh + (size_t)nz * H + kt * 32 + q * 8;
            const float* pn = W_hh + (size_t)nn * H + kt * 32 + q * 8;
            Bhr[kt] = pack8(*(const float4*)pr, *(const float4*)(pr + 4));
            Bhz[kt] = pack8(*(const float4*)pz, *(const float4*)(pz + 4));
            Bhn[kt] = pack8(*(const float4*)pn, *(const float4*)(pn + 4));
        }
#pragma unroll
        for (int kt = 0; kt < 2; ++kt) {
            const float* pr = W_ih + (size_t)nr * D + kt * 32 + q * 8;
            const float* pz = W_ih + (size_t)nz * D + kt * 32 + q * 8;
            const float* pn = W_ih + (size_t)nn * D + kt * 32 + q * 8;
            Bir[kt] = pack8(*(const float4*)pr, *(const float4*)(pr + 4));
            Biz[kt] = pack8(*(const float4*)pz, *(const float4*)(pz + 4));
            Bin[kt] = pack8(*(const float4*)pn, *(const float4*)(pn + 4));
        }
    }

    // ---- per-lane C-row lengths (rows q*4+j) and h state in registers ----
    int  lenc[4];
    float hreg[4];
#pragma unroll
    for (int j = 0; j < 4; ++j) { lenc[j] = slen[q * 4 + j]; hreg[j] = 0.0f; }

    // ---- x staging: thread -> (seq sx, float2 pair px) ----
    const int sx = tid >> 5;        // 0..15
    const int px = tid & 31;        // 0..31 (float2 index)
    const int stx = sstart[sx], lnx = slen[sx];
    const float2* xp = (const float2*)x;

    // stage t=0 into buf0
    {
        float2 x0 = xp[(size_t)(stx + 0) * 32 + px];   // min(0,len-1)=0
        unsigned u = (unsigned)(unsigned short)f2bf(x0.x)
                   | ((unsigned)(unsigned short)f2bf(x0.y) << 16);
        char* xb = (char*)x_bf[0];
        int chunk = (px >> 2) ^ (sx & 7);
        *(unsigned*)(xb + sx * 128 + chunk * 16 + (px & 3) * 4) = u;
    }
    // prefetch t=1
    float2 xnext = xp[(size_t)(stx + min(1, lnx - 1)) * 32 + px];
    __syncthreads();                                    // buf0 + h zeros visible

    const char* hb = (const char*)h_bf;

    for (int t = 0; t < nt; ++t) {
        const int cur = t & 1;
        const char* xb = (const char*)x_bf[cur];

        // ---- A-fragments from LDS (XOR-swizzled, conflict-free b128) ----
        short8 ax[2], ah[4];
#pragma unroll
        for (int kt = 0; kt < 2; ++kt) {
            int chunk = (kt * 4 + q) ^ rsw;             // 0..7
            ax[kt] = *(const short8*)(xb + row * 128 + chunk * 16);
        }
#pragma unroll
        for (int kt = 0; kt < 4; ++kt) {
            int chunk = (kt * 4 + q) ^ rsw;             // 0..15 (xor in low 3 bits)
            ah[kt] = *(const short8*)(hb + row * 256 + chunk * 16);
        }

        // ---- MFMA: gates = x.W_ih^T (+) h.W_hh^T ----
        f32x4 cr = {0.f, 0.f, 0.f, 0.f};
        f32x4 cz = {0.f, 0.f, 0.f, 0.f};
        f32x4 ci = {0.f, 0.f, 0.f, 0.f};   // inn (input part of n-gate)
        f32x4 ch = {0.f, 0.f, 0.f, 0.f};   // hn  (hidden part of n-gate)
#pragma unroll
        for (int kt = 0; kt < 2; ++kt) {
            cr = MFMA(ax[kt], Bir[kt], cr);
            cz = MFMA(ax[kt], Biz[kt], cz);
            ci = MFMA(ax[kt], Bin[kt], ci);
        }
#pragma unroll
        for (int kt = 0; kt < 4; ++kt) {
            cr = MFMA(ah[kt], Bhr[kt], cr);
            cz = MFMA(ah[kt], Bhz[kt], cz);
            ch = MFMA(ah[kt], Bhn[kt], ch);
        }

        // ---- gates + h update (fp32 master state in registers, masked) ----
#pragma unroll
        for (int j = 0; j < 4; ++j) {
            float r  = sigmoid_(cr[j]);
            float zz = sigmoid_(cz[j]);
            float nn = tanh_(ci[j] + r * ch[j]);
            float hn = (1.0f - zz) * nn + zz * hreg[j];
            hreg[j] = (t < lenc[j]) ? hn : hreg[j];
        }

        __syncthreads();    // all h_bf/x_bf reads of this step are done

        // ---- write h (bf16, swizzled) for next step ----
        {
            char* hw = (char*)h_bf;
            const int c = w * 16 + row;                 // h column 0..127
#pragma unroll
            for (int j = 0; j < 4; ++j) {
                int r_ = q * 4 + j;
                int ch_ = (c >> 3) ^ (r_ & 7);
                *(short*)(hw + r_ * 256 + ch_ * 16 + ((c * 2) & 15)) = f2bf(hreg[j]);
            }
        }
        // ---- stage x for t+1 into the other buffer; prefetch t+2 ----
        {
            unsigned u = (unsigned)(unsigned short)f2bf(xnext.x)
                       | ((unsigned)(unsigned short)f2bf(xnext.y) << 16);
            char* xw = (char*)x_bf[cur ^ 1];
            int chunk = (px >> 2) ^ (sx & 7);
            *(unsigned*)(xw + sx * 128 + chunk * 16 + (px & 3) * 4) = u;
            xnext = xp[(size_t)(stx + min(t + 2, lnx - 1)) * 32 + px];
        }
        __syncthreads();    // writes visible for next step
    }

    // ---- epilogue: h -> LDS fp32 ----
    {
        const int c = w * 16 + row;
#pragma unroll
        for (int j = 0; j < 4; ++j) h_f32[q * 4 + j][c] = hreg[j];
    }
    __syncthreads();

    // dense(128->64) + L2 normalize. thread: seq s = tid>>5, cols dd and dd+32.
    {
        const int s  = tid >> 5;
        const int dd = tid & 31;
        float acc0 = b_dense[dd];
        float acc1 = b_dense[dd + 32];
        const float* w0 = W_dense + (size_t)dd * H;
        const float* w1 = W_dense + (size_t)(dd + 32) * H;
#pragma unroll
        for (int j4 = 0; j4 < H; j4 += 4) {
            float4 hv = *(const float4*)&h_f32[s][j4];
            float4 a0 = *(const float4*)(w0 + j4);
            float4 a1 = *(const float4*)(w1 + j4);
            acc0 += hv.x * a0.x + hv.y * a0.y + hv.z * a0.z + hv.w * a0.w;
            acc1 += hv.x * a1.x + hv.y * a1.y + hv.z * a1.z + hv.w * a1.w;
        }
        red[tid] = acc0 * acc0 + acc1 * acc1;
        __syncthreads();
        if (tid < MSEQ) {
            float s2 = 0.f;
#pragma unroll
            for (int k = 0; k < 32; ++k) s2 += red[tid * 32 + k];
            nrm2[tid] = s2;
        }
        __syncthreads();
        float inv = 1.0f / fmaxf(sqrtf(nrm2[s]), 1e-12f);
        int sg = bb * MSEQ + s;
        if (sg < B) {
            out[(size_t)sg * D + dd]      = acc0 * inv;
            out[(size_t)sg * D + dd + 32] = acc1 * inv;
        }
    }
}

extern "C" void kernel_launch(void* const* d_in, const int* in_sizes, int n_in,
                              void* d_out, int out_size, void* d_ws, size_t ws_size,
                              hipStream_t stream) {
    const float* x       = (const float*)d_in[0];
    const int*   offsets = (const int*)d_in[1];
    const float* W_ih    = (const float*)d_in[2];
    const float* W_hh    = (const float*)d_in[3];
    const float* W_dense = (const float*)d_in[4];
    const float* b_dense = (const float*)d_in[5];
    float*       out     = (float*)d_out;

    const int B = in_sizes[1];
    const int T = in_sizes[0] / D;
    const int grid = (B + MSEQ - 1) / MSEQ;

    gru_mfma_kernel<<<grid, 512, 0, stream>>>(x, offsets, W_ih, W_hh, W_dense, b_dense, out, B, T);
}

// Round 4
// 469.708 us; speedup vs baseline: 3.8469x; 1.4321x over previous
//
#include <hip/hip_runtime.h>
#include <math.h>

constexpr int D = 64;      // input / output feature dim
constexpr int H = 128;     // GRU hidden dim
constexpr int MAXLEN = 512;
constexpr int MSEQ = 16;   // sequences per block (MFMA N dim, = lane&15)

typedef __attribute__((ext_vector_type(8))) short short8;  // 8 bf16 = 4 VGPRs
typedef __attribute__((ext_vector_type(4))) float f32x4;   // MFMA accumulator

__device__ __forceinline__ short f2bf(float f) {           // f32 -> bf16 RNE
    unsigned u = __float_as_uint(f);
    u += 0x7fffu + ((u >> 16) & 1u);
    return (short)(u >> 16);
}
__device__ __forceinline__ unsigned f2bf2(float a, float b) {
    return (unsigned)(unsigned short)f2bf(a) | ((unsigned)(unsigned short)f2bf(b) << 16);
}
__device__ __forceinline__ short8 pack8(float4 a, float4 b) {
    short8 r;
    r[0]=f2bf(a.x); r[1]=f2bf(a.y); r[2]=f2bf(a.z); r[3]=f2bf(a.w);
    r[4]=f2bf(b.x); r[5]=f2bf(b.y); r[6]=f2bf(b.z); r[7]=f2bf(b.w);
    return r;
}
__device__ __forceinline__ float rcp_(float x) { return __builtin_amdgcn_rcpf(x); }
__device__ __forceinline__ float sig_(float v) { return rcp_(1.0f + __expf(-v)); }
__device__ __forceinline__ float tanh_(float v) {
    float a = fabsf(v);
    float e = __expf(2.0f * a);
    float t = 1.0f - 2.0f * rcp_(e + 1.0f);
    return copysignf(t, v);
}

#define MFMA(a,b,c) __builtin_amdgcn_mfma_f32_16x16x32_bf16((a),(b),(c),0,0,0)

// 256 threads = 4 waves. SWAPPED operands: gates^T[384,16] = W[384,K] . state^T[K,16].
// A-frag = weight rows (m = lane&15 = gate-row-in-tile, k = (lane>>4)*8+j), registers.
// B-frag = h or x (n = lane&15 = seq, k = (lane>>4)*8+j), from swizzled LDS.
// D: col = lane&15 = seq, row = (lane>>4)*4+reg = gate row  [m89 layout].
// Wave w owns h-feature slice [32w, 32w+32): 6 M-tiles (r,z,n) x (u=0,1).
// h and x double-buffered in LDS -> ONE barrier per step; x prefetch issued at
// step start so the pre-barrier vmcnt(0) drain is covered by MFMA+gate work.
__global__ __launch_bounds__(256, 1)
void gru_mfma4(const float* __restrict__ x,
               const int* __restrict__ offsets,   // int32 (JAX x64 disabled)
               const float* __restrict__ W_ih,
               const float* __restrict__ W_hh,
               const float* __restrict__ W_dense,
               const float* __restrict__ b_dense,
               float* __restrict__ out,
               int B, int T)
{
    const int bb  = blockIdx.x;
    const int tid = threadIdx.x;      // 0..255
    const int w   = tid >> 6;         // wave 0..3
    const int l   = tid & 63;
    const int s   = l & 15;           // seq (B/D n-index) AND A-frag m-index
    const int q   = l >> 4;           // k-group 0..3
    const int sw  = s & 7;            // XOR swizzle key

    __shared__ __align__(16) short h_bf[2][MSEQ * H];   // 2 x 4KB, rows 256B, 16B-chunk XOR swizzle
    __shared__ __align__(16) short x_bf[2][MSEQ * D];   // 2 x 2KB, rows 128B, same swizzle
    __shared__ int slen[MSEQ], sstart[MSEQ];
    __shared__ float h_f32[MSEQ][H];

    // ---- sequence bounds ----
    if (tid < MSEQ) {
        int sg = bb * MSEQ + tid;
        int st = 0, en = 1;
        if (sg < B) { st = offsets[sg]; en = (sg + 1 < B) ? offsets[sg + 1] : T; }
        int ln = en - st;
        ln = max(1, min(ln, MAXLEN));
        sstart[tid] = st; slen[tid] = ln;
    }
    {   // zero h_bf[0] (1024 dwords)
        int* hz = (int*)h_bf[0];
#pragma unroll
        for (int i = 0; i < 4; ++i) hz[tid + 256 * i] = 0;
    }
    __syncthreads();

    int nt = 1;
#pragma unroll
    for (int i = 0; i < MSEQ; ++i) nt = max(nt, slen[i]);

    // ---- A-frags: weight rows in registers (one-time) ----
    short8 Wh[3][2][4];   // [gate][u][kt] over K=128
    short8 Wi[3][2][2];   // [gate][u][kt] over K=64
#pragma unroll
    for (int g = 0; g < 3; ++g) {
#pragma unroll
        for (int u = 0; u < 2; ++u) {
            const int grow = g * H + w * 32 + u * 16 + s;   // row of stacked [3H,*]
            const float* ph = W_hh + (size_t)grow * H + q * 8;
#pragma unroll
            for (int kt = 0; kt < 4; ++kt)
                Wh[g][u][kt] = pack8(*(const float4*)(ph + kt * 32),
                                     *(const float4*)(ph + kt * 32 + 4));
            const float* pi = W_ih + (size_t)grow * D + q * 8;
#pragma unroll
            for (int kt = 0; kt < 2; ++kt)
                Wi[g][u][kt] = pack8(*(const float4*)(pi + kt * 32),
                                     *(const float4*)(pi + kt * 32 + 4));
        }
    }

    // ---- per-lane LDS byte offsets (swizzled) ----
    int hoff[4], xoff[2], woff[2];
#pragma unroll
    for (int kt = 0; kt < 4; ++kt) hoff[kt] = s * 256 + (((kt * 4 + q) ^ sw) << 4);
#pragma unroll
    for (int kt = 0; kt < 2; ++kt) xoff[kt] = s * 128 + (((kt * 4 + q) ^ sw) << 4);
#pragma unroll
    for (int u = 0; u < 2; ++u)
        woff[u] = s * 256 + (((w * 4 + u * 2 + (q >> 1)) ^ sw) << 4) + ((q & 1) << 3);

    // ---- x staging map: thread -> (seq ss, float4 chunk fc) ----
    const int ss = tid >> 4;          // 0..15
    const int fc = tid & 15;          // 0..15
    const int st_s = sstart[ss];
    const int ln_s = slen[ss];
    const float* xb_g = x + (size_t)st_s * D + fc * 4;
    const int xwoff = ss * 128 + (((fc >> 1) ^ (ss & 7)) << 4) + ((fc & 1) << 3);

    {   // stage x row 0 into buf 0
        float4 v = *(const float4*)(xb_g);
        uint2 pr = { f2bf2(v.x, v.y), f2bf2(v.z, v.w) };
        *(uint2*)((char*)x_bf[0] + xwoff) = pr;
    }

    const int lenS = slen[s];
    float hreg[2][4] = {{0.f,0.f,0.f,0.f},{0.f,0.f,0.f,0.f}};

    __syncthreads();                  // x_bf[0], h_bf[0] visible

    for (int t = 0; t < nt; ++t) {
        const int p = t & 1;
        const char* hb = (const char*)h_bf[p];
        const char* xb = (const char*)x_bf[p];

        // B-frags for this step
        short8 bh[4], bx[2];
#pragma unroll
        for (int kt = 0; kt < 4; ++kt) bh[kt] = *(const short8*)(hb + hoff[kt]);
#pragma unroll
        for (int kt = 0; kt < 2; ++kt) bx[kt] = *(const short8*)(xb + xoff[kt]);

        // prefetch x row t+1 NOW; latency hides under MFMA+gate before barrier
        const int tn = (t + 1 < ln_s) ? t + 1 : ln_s - 1;
        float4 xpf = *(const float4*)(xb_g + (size_t)tn * D);

        // 36 MFMAs: gates^T = W . state^T
        f32x4 cr[2] = {{0,0,0,0},{0,0,0,0}};
        f32x4 cz[2] = {{0,0,0,0},{0,0,0,0}};
        f32x4 ci[2] = {{0,0,0,0},{0,0,0,0}};
        f32x4 chh[2]= {{0,0,0,0},{0,0,0,0}};
#pragma unroll
        for (int u = 0; u < 2; ++u) {
#pragma unroll
            for (int kt = 0; kt < 2; ++kt) {
                cr[u] = MFMA(Wi[0][u][kt], bx[kt], cr[u]);
                cz[u] = MFMA(Wi[1][u][kt], bx[kt], cz[u]);
                ci[u] = MFMA(Wi[2][u][kt], bx[kt], ci[u]);
            }
#pragma unroll
            for (int kt = 0; kt < 4; ++kt) {
                cr[u]  = MFMA(Wh[0][u][kt], bh[kt], cr[u]);
                cz[u]  = MFMA(Wh[1][u][kt], bh[kt], cz[u]);
                chh[u] = MFMA(Wh[2][u][kt], bh[kt], chh[u]);
            }
        }

        // gates + masked h update (fp32 master state, lane-local per seq)
        const bool upd = (t < lenS);
#pragma unroll
        for (int u = 0; u < 2; ++u) {
#pragma unroll
            for (int j = 0; j < 4; ++j) {
                float r  = sig_(cr[u][j]);
                float z  = sig_(cz[u][j]);
                float n  = tanh_(ci[u][j] + r * chh[u][j]);
                float hn = (1.0f - z) * n + z * hreg[u][j];
                hreg[u][j] = upd ? hn : hreg[u][j];
            }
        }

        // write h' (2 x b64, conflict-free) and stage x(t+1) into buf p^1
        {
            char* hw = (char*)h_bf[p ^ 1];
#pragma unroll
            for (int u = 0; u < 2; ++u) {
                uint2 pr = { f2bf2(hreg[u][0], hreg[u][1]),
                             f2bf2(hreg[u][2], hreg[u][3]) };
                *(uint2*)(hw + woff[u]) = pr;
            }
            uint2 px = { f2bf2(xpf.x, xpf.y), f2bf2(xpf.z, xpf.w) };
            *(uint2*)((char*)x_bf[p ^ 1] + xwoff) = px;
        }
        __syncthreads();   // single barrier: publishes buf p^1, closes reads of p
    }

    // ---- epilogue: h -> LDS fp32 (features w*32+u*16+q*4 .. +4 are contiguous) ----
#pragma unroll
    for (int u = 0; u < 2; ++u) {
        float4 hv = { hreg[u][0], hreg[u][1], hreg[u][2], hreg[u][3] };
        *(float4*)&h_f32[s][w * 32 + u * 16 + q * 4] = hv;
    }
    __syncthreads();

    // dense(128->64) + L2 normalize: 16 threads per seq, 4 cols each
    {
        const int s2 = tid >> 4;      // seq
        const int cb = tid & 15;      // col base
        float acc[4];
#pragma unroll
        for (int k = 0; k < 4; ++k) acc[k] = b_dense[cb + 16 * k];
#pragma unroll
        for (int k = 0; k < 4; ++k) {
            const float* wd = W_dense + (size_t)(cb + 16 * k) * H;
            float a0=0.f,a1=0.f,a2=0.f,a3=0.f;
#pragma unroll
            for (int j = 0; j < H; j += 4) {
                float4 hv = *(const float4*)&h_f32[s2][j];
                float4 wv = *(const float4*)(wd + j);
                a0 += hv.x*wv.x; a1 += hv.y*wv.y; a2 += hv.z*wv.z; a3 += hv.w*wv.w;
            }
            acc[k] += (a0 + a1) + (a2 + a3);
        }
        float s2q = acc[0]*acc[0] + acc[1]*acc[1] + acc[2]*acc[2] + acc[3]*acc[3];
#pragma unroll
        for (int off = 8; off >= 1; off >>= 1) s2q += __shfl_xor(s2q, off);
        float invn = 1.0f / fmaxf(sqrtf(s2q), 1e-12f);
        int sg = bb * MSEQ + s2;
        if (sg < B) {
#pragma unroll
            for (int k = 0; k < 4; ++k)
                out[(size_t)sg * D + cb + 16 * k] = acc[k] * invn;
        }
    }
}

extern "C" void kernel_launch(void* const* d_in, const int* in_sizes, int n_in,
                              void* d_out, int out_size, void* d_ws, size_t ws_size,
                              hipStream_t stream) {
    const float* x       = (const float*)d_in[0];
    const int*   offsets = (const int*)d_in[1];
    const float* W_ih    = (const float*)d_in[2];
    const float* W_hh    = (const float*)d_in[3];
    const float* W_dense = (const float*)d_in[4];
    const float* b_dense = (const float*)d_in[5];
    float*       out     = (float*)d_out;

    const int B = in_sizes[1];
    const int T = in_sizes[0] / D;
    const int grid = (B + MSEQ - 1) / MSEQ;

    gru_mfma4<<<grid, 256, 0, stream>>>(x, offsets, W_ih, W_hh, W_dense, b_dense, out, B, T);
}

// Round 5
// 430.836 us; speedup vs baseline: 4.1940x; 1.0902x over previous
//
#include <hip/hip_runtime.h>
#include <math.h>

constexpr int D = 64;      // input / output feature dim
constexpr int H = 128;     // GRU hidden dim
constexpr int MAXLEN = 512;
constexpr int MSEQ = 16;   // sequences per block (MFMA N dim, = lane&15)

typedef __attribute__((ext_vector_type(8))) short short8;  // 8 bf16 = 4 VGPRs
typedef __attribute__((ext_vector_type(4))) float f32x4;   // MFMA accumulator

__device__ __forceinline__ short f2bf(float f) {           // f32 -> bf16 RNE
    unsigned u = __float_as_uint(f);
    u += 0x7fffu + ((u >> 16) & 1u);
    return (short)(u >> 16);
}
__device__ __forceinline__ unsigned f2bf2(float a, float b) {
    return (unsigned)(unsigned short)f2bf(a) | ((unsigned)(unsigned short)f2bf(b) << 16);
}
__device__ __forceinline__ short8 pack8(float4 a, float4 b) {
    short8 r;
    r[0]=f2bf(a.x); r[1]=f2bf(a.y); r[2]=f2bf(a.z); r[3]=f2bf(a.w);
    r[4]=f2bf(b.x); r[5]=f2bf(b.y); r[6]=f2bf(b.z); r[7]=f2bf(b.w);
    return r;
}
__device__ __forceinline__ float rcp_(float x) { return __builtin_amdgcn_rcpf(x); }
__device__ __forceinline__ float sig_(float v) { return rcp_(1.0f + __expf(-v)); }
__device__ __forceinline__ float tanh_(float v) {
    float a = fabsf(v);
    float e = __expf(2.0f * a);
    float t = 1.0f - 2.0f * rcp_(e + 1.0f);
    return copysignf(t, v);
}

#define MFMA(a,b,c) __builtin_amdgcn_mfma_f32_16x16x32_bf16((a),(b),(c),0,0,0)

// 512 threads = 8 waves, 2 waves/SIMD (the round-4 version had 1/SIMD: all
// latency exposed). Swapped operands: gates^T[384,16] = W[384,K] . state^T[K,16].
// Wave w owns feature rows [16w,16w+16) of ALL THREE gates -> per lane 4 h
// values, r/z/n collocated. A-frag = weight rows (registers, loaded once).
// B-frag = h or x from XOR-swizzled double-buffered LDS. One barrier/step.
__global__ __launch_bounds__(512, 2)
void gru_mfma8(const float* __restrict__ x,
               const int* __restrict__ offsets,   // int32 (JAX x64 disabled)
               const float* __restrict__ W_ih,
               const float* __restrict__ W_hh,
               const float* __restrict__ W_dense,
               const float* __restrict__ b_dense,
               float* __restrict__ out,
               int B, int T)
{
    const int bb  = blockIdx.x;
    const int tid = threadIdx.x;      // 0..511
    const int w   = tid >> 6;         // wave 0..7
    const int l   = tid & 63;
    const int s   = l & 15;           // seq (B/D n-index) AND A-frag m-index
    const int q   = l >> 4;           // k-group 0..3
    const int sw  = s & 7;            // XOR swizzle key

    __shared__ __align__(16) short h_bf[2][MSEQ * H];   // 2 x 4KB, row 256B, 16B-chunk XOR swizzle
    __shared__ __align__(16) short x_bf[2][MSEQ * D];   // 2 x 2KB, row 128B, same swizzle
    __shared__ int slen[MSEQ], sstart[MSEQ];
    __shared__ float h_f32[MSEQ][H];

    // ---- sequence bounds ----
    if (tid < MSEQ) {
        int sg = bb * MSEQ + tid;
        int st = 0, en = 1;
        if (sg < B) { st = offsets[sg]; en = (sg + 1 < B) ? offsets[sg + 1] : T; }
        int ln = en - st;
        ln = max(1, min(ln, MAXLEN));
        sstart[tid] = st; slen[tid] = ln;
    }
    {   // zero h_bf[0] (1024 dwords, 512 threads x 2)
        int* hz = (int*)h_bf[0];
        hz[tid] = 0; hz[tid + 512] = 0;
    }
    __syncthreads();

    int nt = 1;
#pragma unroll
    for (int i = 0; i < MSEQ; ++i) nt = max(nt, slen[i]);

    // ---- A-frags: weight rows in registers (one-time). Row = g*H + w*16 + s ----
    short8 Wh[3][4];   // [gate][kt], K=128
    short8 Wi[3][2];   // [gate][kt], K=64
#pragma unroll
    for (int g = 0; g < 3; ++g) {
        const int grow = g * H + w * 16 + s;
        const float* ph = W_hh + (size_t)grow * H + q * 8;
#pragma unroll
        for (int kt = 0; kt < 4; ++kt)
            Wh[g][kt] = pack8(*(const float4*)(ph + kt * 32),
                              *(const float4*)(ph + kt * 32 + 4));
        const float* pi = W_ih + (size_t)grow * D + q * 8;
#pragma unroll
        for (int kt = 0; kt < 2; ++kt)
            Wi[g][kt] = pack8(*(const float4*)(pi + kt * 32),
                              *(const float4*)(pi + kt * 32 + 4));
    }

    // ---- per-lane LDS byte offsets (swizzled) ----
    int hoff[4], xoff[2];
#pragma unroll
    for (int kt = 0; kt < 4; ++kt) hoff[kt] = s * 256 + (((kt * 4 + q) ^ sw) << 4);
#pragma unroll
    for (int kt = 0; kt < 2; ++kt) xoff[kt] = s * 128 + (((kt * 4 + q) ^ sw) << 4);
    // h write: features f0 = w*16 + q*4 (4 contiguous bf16 = 8B) at row s
    const int woff = s * 256 + ((((2 * w) + (q >> 1)) ^ sw) << 4) + ((q & 1) << 3);

    // ---- x staging map: thread -> (seq ss, float2 pxx) ----
    const int ss  = tid >> 5;         // 0..15
    const int pxx = tid & 31;         // 0..31
    const int st_s = sstart[ss];
    const int ln_s = slen[ss];
    const float* xg = x + (size_t)st_s * D + pxx * 2;
    const int xwoff = ss * 128 + ((((pxx >> 2) ^ (ss & 7)) << 4)) + ((pxx & 3) << 2);

    {   // stage x row 0 into buf 0
        float2 v = *(const float2*)xg;
        *(unsigned*)((char*)x_bf[0] + xwoff) = f2bf2(v.x, v.y);
    }
    // prefetch x row 1
    float2 xpf = *(const float2*)(xg + (size_t)min(1, ln_s - 1) * D);

    const int lenS = slen[s];
    float hreg[4] = {0.f, 0.f, 0.f, 0.f};

    __syncthreads();                  // x_bf[0], h_bf[0] visible

    for (int t = 0; t < nt; ++t) {
        const int p = t & 1;
        const char* hb = (const char*)h_bf[p];
        const char* xb = (const char*)x_bf[p];

        short8 bh[4], bx[2];
#pragma unroll
        for (int kt = 0; kt < 4; ++kt) bh[kt] = *(const short8*)(hb + hoff[kt]);
#pragma unroll
        for (int kt = 0; kt < 2; ++kt) bx[kt] = *(const short8*)(xb + xoff[kt]);

        // 18 MFMAs: gates^T = W . state^T  (4 independent chains)
        f32x4 cr = {0,0,0,0}, cz = {0,0,0,0}, ci = {0,0,0,0}, chh = {0,0,0,0};
#pragma unroll
        for (int kt = 0; kt < 2; ++kt) {
            cr = MFMA(Wi[0][kt], bx[kt], cr);
            cz = MFMA(Wi[1][kt], bx[kt], cz);
            ci = MFMA(Wi[2][kt], bx[kt], ci);
        }
#pragma unroll
        for (int kt = 0; kt < 4; ++kt) {
            cr  = MFMA(Wh[0][kt], bh[kt], cr);
            cz  = MFMA(Wh[1][kt], bh[kt], cz);
            chh = MFMA(Wh[2][kt], bh[kt], chh);
        }

        // gates + masked h update (fp32 master state, lane-local)
        const bool upd = (t < lenS);
#pragma unroll
        for (int j = 0; j < 4; ++j) {
            float r  = sig_(cr[j]);
            float z  = sig_(cz[j]);
            float n  = tanh_(ci[j] + r * chh[j]);
            float hn = (1.0f - z) * n + z * hreg[j];
            hreg[j] = upd ? hn : hreg[j];
        }

        // write h' (one b64, conflict-free) + stage x(t+1) into buf p^1
        {
            char* hw = (char*)h_bf[p ^ 1];
            uint2 pr = { f2bf2(hreg[0], hreg[1]), f2bf2(hreg[2], hreg[3]) };
            *(uint2*)(hw + woff) = pr;
            *(unsigned*)((char*)x_bf[p ^ 1] + xwoff) = f2bf2(xpf.x, xpf.y);
        }
        // prefetch x row t+2 (consumed next step; drained at this barrier,
        // latency covered by this step's MFMA+VALU)
        {
            const int tn = (t + 2 < ln_s) ? t + 2 : ln_s - 1;
            xpf = *(const float2*)(xg + (size_t)tn * D);
        }
        __syncthreads();   // single barrier: publishes buf p^1, closes reads of p
    }

    // ---- epilogue: h -> LDS fp32 ----
    {
        float4 hv = { hreg[0], hreg[1], hreg[2], hreg[3] };
        *(float4*)&h_f32[s][w * 16 + q * 4] = hv;
    }
    __syncthreads();

    // dense(128->64) + L2 normalize: 32 threads per seq, 2 cols each
    {
        const int s2 = tid >> 5;      // seq
        const int cb = tid & 31;      // col base (cols cb, cb+32)
        float acc0 = b_dense[cb];
        float acc1 = b_dense[cb + 32];
        const float* w0 = W_dense + (size_t)cb * H;
        const float* w1 = W_dense + (size_t)(cb + 32) * H;
#pragma unroll
        for (int j = 0; j < H; j += 4) {
            float4 hv = *(const float4*)&h_f32[s2][j];
            float4 a0 = *(const float4*)(w0 + j);
            float4 a1 = *(const float4*)(w1 + j);
            acc0 += hv.x*a0.x + hv.y*a0.y + hv.z*a0.z + hv.w*a0.w;
            acc1 += hv.x*a1.x + hv.y*a1.y + hv.z*a1.z + hv.w*a1.w;
        }
        float s2q = acc0 * acc0 + acc1 * acc1;
#pragma unroll
        for (int off = 16; off >= 1; off >>= 1) s2q += __shfl_xor(s2q, off);
        float invn = 1.0f / fmaxf(sqrtf(s2q), 1e-12f);
        int sg = bb * MSEQ + s2;
        if (sg < B) {
            out[(size_t)sg * D + cb]      = acc0 * invn;
            out[(size_t)sg * D + cb + 32] = acc1 * invn;
        }
    }
}

extern "C" void kernel_launch(void* const* d_in, const int* in_sizes, int n_in,
                              void* d_out, int out_size, void* d_ws, size_t ws_size,
                              hipStream_t stream) {
    const float* x       = (const float*)d_in[0];
    const int*   offsets = (const int*)d_in[1];
    const float* W_ih    = (const float*)d_in[2];
    const float* W_hh    = (const float*)d_in[3];
    const float* W_dense = (const float*)d_in[4];
    const float* b_dense = (const float*)d_in[5];
    float*       out     = (float*)d_out;

    const int B = in_sizes[1];
    const int T = in_sizes[0] / D;
    const int grid = (B + MSEQ - 1) / MSEQ;

    gru_mfma8<<<grid, 512, 0, stream>>>(x, offsets, W_ih, W_hh, W_dense, b_dense, out, B, T);
}

// Round 6
// 398.843 us; speedup vs baseline: 4.5304x; 1.0802x over previous
//
#include <hip/hip_runtime.h>
#include <math.h>

constexpr int D = 64;      // input / output feature dim
constexpr int H = 128;     // GRU hidden dim
constexpr int MAXLEN = 512;
constexpr int MSEQ = 16;   // sequences per block (MFMA N dim, = lane&15)

typedef __attribute__((ext_vector_type(8))) short short8;  // 8 bf16 = 4 VGPRs
typedef __attribute__((ext_vector_type(4))) float f32x4;   // MFMA accumulator

__device__ __forceinline__ short f2bf(float f) {           // f32 -> bf16 RNE (host-side packs)
    unsigned u = __float_as_uint(f);
    u += 0x7fffu + ((u >> 16) & 1u);
    return (short)(u >> 16);
}
// HW packed convert: 2 x f32 -> 2 x bf16 (RNE), single VALU instr
__device__ __forceinline__ unsigned cvtpk(float a, float b) {
    unsigned r;
    asm volatile("v_cvt_pk_bf16_f32 %0, %1, %2" : "=v"(r) : "v"(a), "v"(b));
    return r;
}
__device__ __forceinline__ short8 pack8(float4 a, float4 b) {
    short8 r;
    r[0]=f2bf(a.x); r[1]=f2bf(a.y); r[2]=f2bf(a.z); r[3]=f2bf(a.w);
    r[4]=f2bf(b.x); r[5]=f2bf(b.y); r[6]=f2bf(b.z); r[7]=f2bf(b.w);
    return r;
}
__device__ __forceinline__ float rcp_(float x) { return __builtin_amdgcn_rcpf(x); }
__device__ __forceinline__ float sig_(float v) { return rcp_(1.0f + __expf(-v)); }
__device__ __forceinline__ float tanh_(float v) {
    float a = fabsf(v);
    float e = __expf(2.0f * a);
    float t = 1.0f - 2.0f * rcp_(e + 1.0f);
    return copysignf(t, v);
}

// lgkm-only barrier: drains LDS ops (producer->consumer) but does NOT drain
// vmcnt -- the x prefetch stays in flight across the barrier (T4 pattern).
// Safe: loop trip count is block-uniform; "memory" clobber pins LDS op order.
__device__ __forceinline__ void lgkm_barrier() {
    asm volatile("s_waitcnt lgkmcnt(0)\n\ts_barrier" ::: "memory");
}

#define MFMA(a,b,c) __builtin_amdgcn_mfma_f32_16x16x32_bf16((a),(b),(c),0,0,0)

// 512 threads = 8 waves, 2 waves/SIMD. Swapped operands:
// gates^T[384,16] = W[384,K] . state^T[K,16].
// Wave w owns feature rows [16w,16w+16) of ALL THREE gates -> per lane 4 h
// values, r/z/n collocated. A-frag = weight rows (registers, loaded once).
// B-frag = h or x from XOR-swizzled double-buffered LDS. One lgkm-only
// barrier per step; x global prefetch never drained at the barrier.
__global__ __launch_bounds__(512, 2)
void gru_mfma8(const float* __restrict__ x,
               const int* __restrict__ offsets,   // int32 (JAX x64 disabled)
               const float* __restrict__ W_ih,
               const float* __restrict__ W_hh,
               const float* __restrict__ W_dense,
               const float* __restrict__ b_dense,
               float* __restrict__ out,
               int B, int T)
{
    const int bb  = blockIdx.x;
    const int tid = threadIdx.x;      // 0..511
    const int w   = tid >> 6;         // wave 0..7
    const int l   = tid & 63;
    const int s   = l & 15;           // seq (B/D n-index) AND A-frag m-index
    const int q   = l >> 4;           // k-group 0..3
    const int sw  = s & 7;            // XOR swizzle key

    __shared__ __align__(16) short h_bf[2][MSEQ * H];   // 2 x 4KB, row 256B, 16B-chunk XOR swizzle
    __shared__ __align__(16) short x_bf[2][MSEQ * D];   // 2 x 2KB, row 128B, same swizzle
    __shared__ int slen[MSEQ], sstart[MSEQ];
    __shared__ float h_f32[MSEQ][H];

    // ---- sequence bounds ----
    if (tid < MSEQ) {
        int sg = bb * MSEQ + tid;
        int st = 0, en = 1;
        if (sg < B) { st = offsets[sg]; en = (sg + 1 < B) ? offsets[sg + 1] : T; }
        int ln = en - st;
        ln = max(1, min(ln, MAXLEN));
        sstart[tid] = st; slen[tid] = ln;
    }
    {   // zero h_bf[0] (1024 dwords, 512 threads x 2)
        int* hz = (int*)h_bf[0];
        hz[tid] = 0; hz[tid + 512] = 0;
    }
    __syncthreads();

    int nt = 1;
#pragma unroll
    for (int i = 0; i < MSEQ; ++i) nt = max(nt, slen[i]);

    // ---- A-frags: weight rows in registers (one-time). Row = g*H + w*16 + s ----
    short8 Wh[3][4];   // [gate][kt], K=128
    short8 Wi[3][2];   // [gate][kt], K=64
#pragma unroll
    for (int g = 0; g < 3; ++g) {
        const int grow = g * H + w * 16 + s;
        const float* ph = W_hh + (size_t)grow * H + q * 8;
#pragma unroll
        for (int kt = 0; kt < 4; ++kt)
            Wh[g][kt] = pack8(*(const float4*)(ph + kt * 32),
                              *(const float4*)(ph + kt * 32 + 4));
        const float* pi = W_ih + (size_t)grow * D + q * 8;
#pragma unroll
        for (int kt = 0; kt < 2; ++kt)
            Wi[g][kt] = pack8(*(const float4*)(pi + kt * 32),
                              *(const float4*)(pi + kt * 32 + 4));
    }

    // ---- per-lane LDS byte offsets (swizzled) ----
    int hoff[4], xoff[2];
#pragma unroll
    for (int kt = 0; kt < 4; ++kt) hoff[kt] = s * 256 + (((kt * 4 + q) ^ sw) << 4);
#pragma unroll
    for (int kt = 0; kt < 2; ++kt) xoff[kt] = s * 128 + (((kt * 4 + q) ^ sw) << 4);
    // h write: features f0 = w*16 + q*4 (4 contiguous bf16 = 8B) at row s
    const int woff = s * 256 + ((((2 * w) + (q >> 1)) ^ sw) << 4) + ((q & 1) << 3);

    // ---- x staging map: thread -> (seq ss, float2 pxx) ----
    const int ss  = tid >> 5;         // 0..15
    const int pxx = tid & 31;         // 0..31
    const int st_s = sstart[ss];
    const int ln_s = slen[ss];
    const float* xg = x + (size_t)st_s * D + pxx * 2;
    const int xwoff = ss * 128 + ((((pxx >> 2) ^ (ss & 7)) << 4)) + ((pxx & 3) << 2);

    {   // stage x row 0 into buf 0
        float2 v = *(const float2*)xg;
        *(unsigned*)((char*)x_bf[0] + xwoff) = cvtpk(v.x, v.y);
    }
    // prefetch x row 1 (consumed at step 0's staging write)
    float2 xpf = *(const float2*)(xg + (size_t)min(1, ln_s - 1) * D);

    const int lenS = slen[s];
    float hreg[4] = {0.f, 0.f, 0.f, 0.f};

    __syncthreads();                  // x_bf[0], h_bf[0] visible

    for (int t = 0; t < nt; ++t) {
        const int p = t & 1;
        const char* hb = (const char*)h_bf[p];
        const char* xb = (const char*)x_bf[p];

        short8 bh[4], bx[2];
#pragma unroll
        for (int kt = 0; kt < 4; ++kt) bh[kt] = *(const short8*)(hb + hoff[kt]);
#pragma unroll
        for (int kt = 0; kt < 2; ++kt) bx[kt] = *(const short8*)(xb + xoff[kt]);

        // issue x(t+2) prefetch NOW into a fresh register (max slack; its
        // vmcnt wait lands before NEXT step's staging write, not at a barrier)
        const int tn = (t + 2 < ln_s) ? t + 2 : ln_s - 1;
        float2 xnew = *(const float2*)(xg + (size_t)tn * D);

        // 18 MFMAs: gates^T = W . state^T  (4 independent chains)
        f32x4 cr = {0,0,0,0}, cz = {0,0,0,0}, ci = {0,0,0,0}, chh = {0,0,0,0};
#pragma unroll
        for (int kt = 0; kt < 2; ++kt) {
            cr = MFMA(Wi[0][kt], bx[kt], cr);
            cz = MFMA(Wi[1][kt], bx[kt], cz);
            ci = MFMA(Wi[2][kt], bx[kt], ci);
        }
#pragma unroll
        for (int kt = 0; kt < 4; ++kt) {
            cr  = MFMA(Wh[0][kt], bh[kt], cr);
            cz  = MFMA(Wh[1][kt], bh[kt], cz);
            chh = MFMA(Wh[2][kt], bh[kt], chh);
        }

        // gates + masked h update (fp32 master state, lane-local)
        const bool upd = (t < lenS);
#pragma unroll
        for (int j = 0; j < 4; ++j) {
            float r  = sig_(cr[j]);
            float z  = sig_(cz[j]);
            float n  = tanh_(ci[j] + r * chh[j]);
            float hn = (1.0f - z) * n + z * hreg[j];
            hreg[j] = upd ? hn : hreg[j];
        }

        // write h' (one b64, conflict-free) + stage x(t+1) into buf p^1
        {
            char* hw = (char*)h_bf[p ^ 1];
            uint2 pr = { cvtpk(hreg[0], hreg[1]), cvtpk(hreg[2], hreg[3]) };
            *(uint2*)(hw + woff) = pr;
            *(unsigned*)((char*)x_bf[p ^ 1] + xwoff) = cvtpk(xpf.x, xpf.y);
        }
        xpf = xnew;        // rotate prefetch register

        lgkm_barrier();    // drains LDS only; x prefetch stays in flight
    }

    // ---- epilogue: h -> LDS fp32 ----
    {
        float4 hv = { hreg[0], hreg[1], hreg[2], hreg[3] };
        *(float4*)&h_f32[s][w * 16 + q * 4] = hv;
    }
    __syncthreads();

    // dense(128->64) + L2 normalize: 32 threads per seq, 2 cols each
    {
        const int s2 = tid >> 5;      // seq
        const int cb = tid & 31;      // col base (cols cb, cb+32)
        float acc0 = b_dense[cb];
        float acc1 = b_dense[cb + 32];
        const float* w0 = W_dense + (size_t)cb * H;
        const float* w1 = W_dense + (size_t)(cb + 32) * H;
#pragma unroll
        for (int j = 0; j < H; j += 4) {
            float4 hv = *(const float4*)&h_f32[s2][j];
            float4 a0 = *(const float4*)(w0 + j);
            float4 a1 = *(const float4*)(w1 + j);
            acc0 += hv.x*a0.x + hv.y*a0.y + hv.z*a0.z + hv.w*a0.w;
            acc1 += hv.x*a1.x + hv.y*a1.y + hv.z*a1.z + hv.w*a1.w;
        }
        float s2q = acc0 * acc0 + acc1 * acc1;
#pragma unroll
        for (int off = 16; off >= 1; off >>= 1) s2q += __shfl_xor(s2q, off);
        float invn = 1.0f / fmaxf(sqrtf(s2q), 1e-12f);
        int sg = bb * MSEQ + s2;
        if (sg < B) {
            out[(size_t)sg * D + cb]      = acc0 * invn;
            out[(size_t)sg * D + cb + 32] = acc1 * invn;
        }
    }
}

extern "C" void kernel_launch(void* const* d_in, const int* in_sizes, int n_in,
                              void* d_out, int out_size, void* d_ws, size_t ws_size,
                              hipStream_t stream) {
    const float* x       = (const float*)d_in[0];
    const int*   offsets = (const int*)d_in[1];
    const float* W_ih    = (const float*)d_in[2];
    const float* W_hh    = (const float*)d_in[3];
    const float* W_dense = (const float*)d_in[4];
    const float* b_dense = (const float*)d_in[5];
    float*       out     = (float*)d_out;

    const int B = in_sizes[1];
    const int T = in_sizes[0] / D;
    const int grid = (B + MSEQ - 1) / MSEQ;

    gru_mfma8<<<grid, 512, 0, stream>>>(x, offsets, W_ih, W_hh, W_dense, b_dense, out, B, T);
}